// Round 13
// baseline (76.018 us; speedup 1.0000x reference)
//
#include <hip/hip_runtime.h>
#include <stdint.h>

#define L_DIM 64
#define R_DIM 2048
#define M_DIM 512      // B*F
#define K_DIM 4096     // 2*R (concat arg1|arg2 along K)
#define N_DIM 2048

typedef _Float16 half_t;
typedef _Float16 half4 __attribute__((ext_vector_type(4)));
typedef _Float16 half8 __attribute__((ext_vector_type(8)));
typedef float f4 __attribute__((ext_vector_type(4)));
typedef float floatx4 __attribute__((ext_vector_type(4)));

// ---------------- kernel 1: front (513 blocks x 512 thr) ----------------
// blocks 0..511 : weighted reduce over L -> Ah [512][4096] fp16
// block  512    : w1/w2 row maxes
__global__ __launch_bounds__(512) void k_front(
    const float* __restrict__ x, const float* __restrict__ w1,
    const float* __restrict__ w2, half_t* __restrict__ Ah,
    float* __restrict__ out)
{
    const int tid = threadIdx.x;
    const int bid = blockIdx.x;

    if (bid < 512) {
        __shared__ float w1s[L_DIM], w2s[L_DIM];
        const int bf = bid;
        const int b  = bf >> 6;
        const int f  = bf & 63;
        if (tid < L_DIM) {
            w1s[tid] = w1[b * L_DIM + tid];
            w2s[tid] = w2[b * L_DIM + tid];
        }
        __syncthreads();
        const int r0 = tid * 4;                     // 512*4 = 2048 = R
        const f4* xp = (const f4*)(x + ((size_t)(b * 4096 + f)) * 2048 + r0);
        float a1x=0.f,a1y=0.f,a1z=0.f,a1w=0.f;
        float a2x=0.f,a2y=0.f,a2z=0.f,a2w=0.f;
        #pragma unroll 8
        for (int l = 0; l < L_DIM; ++l) {
            f4 v = __builtin_nontemporal_load(xp + (size_t)l * (64 * R_DIM / 4));
            float u1 = w1s[l], u2 = w2s[l];
            a1x += v.x*u1; a1y += v.y*u1; a1z += v.z*u1; a1w += v.w*u1;
            a2x += v.x*u2; a2y += v.y*u2; a2z += v.z*u2; a2w += v.w*u2;
        }
        half4 h1 = { (half_t)a1x, (half_t)a1y, (half_t)a1z, (half_t)a1w };
        half4 h2 = { (half_t)a2x, (half_t)a2y, (half_t)a2z, (half_t)a2w };
        *(half4*)(Ah + (size_t)bf * K_DIM + r0) = h1;
        *(half4*)(Ah + (size_t)bf * K_DIM + R_DIM + r0) = h2;
    } else {
        if (tid < 16) {
            const float* src = (tid < 8) ? w1 : w2;
            const int b8 = tid & 7;
            float m = -1.f;
            #pragma unroll 8
            for (int l = 0; l < L_DIM; ++l)
                m = fmaxf(m, src[b8 * L_DIM + l]);
            out[(size_t)M_DIM * N_DIM + tid] = m;
        }
    }
}

// ---------------- kernel 2: MFMA GEMM, 128x64 tiles, splitK=4 ----------------
// A staged via global_load_lds (fp16 from ws). B staged from cons fp32
// directly: load-early -> convert -> swizzled ds_write after MFMA (T14).
__device__ __forceinline__ void gload16(void* lds, const void* g)
{
    __builtin_amdgcn_global_load_lds(
        (const __attribute__((address_space(1))) void*)g,
        (__attribute__((address_space(3))) void*)lds, 16, 0, 0);
}

#define BM 128
#define BN 64
#define BK 64
#define SPLITK 4
#define KSEG (K_DIM / SPLITK)  // 1024
#define NSTEP (KSEG / BK)      // 16

__global__ __launch_bounds__(256) void k_gemm(
    const half_t* __restrict__ Ah, const float* __restrict__ cl,
    const float* __restrict__ cr, float* __restrict__ part)
{
    __shared__ half_t sA[2][BM * BK];
    __shared__ half_t sB[2][BN * BK];
    const int tid  = threadIdx.x;
    const int lane = tid & 63;
    const int w    = tid >> 6;           // wave 0..3
    const int wr   = w >> 1, wc = w & 1; // 2x2 wave grid, 64x32 each
    const int m0   = blockIdx.y * BM;
    const int n0   = blockIdx.x * BN;
    const int z    = blockIdx.z;
    const int kz   = z * KSEG;

    const int srow = lane >> 3;                    // row within 8-row chunk
    const int p8   = lane & 7;                     // physical 8-half slot
    const int scol = (p8 ^ srow) << 3;             // swizzled source col (halfs)
    // B source: z<2 -> cons_l (k in [0,2048)), z>=2 -> cons_r
    const float* csrc = (z < 2) ? cl : cr;

    const floatx4 fzero = { 0.f, 0.f, 0.f, 0.f };
    floatx4 acc[4][2];
    #pragma unroll
    for (int i = 0; i < 4; ++i)
        #pragma unroll
        for (int j = 0; j < 2; ++j) acc[i][j] = fzero;

    auto stageA = [&](int buf, int kt) {
        #pragma unroll
        for (int c = 0; c < 4; ++c) {
            const int rbase = w * 32 + c * 8;      // wave-uniform, 128 rows
            const int row   = rbase + srow;
            gload16(&sA[buf][rbase * BK], Ah + (size_t)(m0 + row) * K_DIM + kt + scol);
        }
    };
    // load B fp32 into regs (issue early; swizzle folded into source col)
    auto loadB = [&](int kt, f4* regs) {
        const int ck = (kt & 2047) + scol;
        #pragma unroll
        for (int c = 0; c < 2; ++c) {
            const int row = w * 16 + c * 8 + srow; // 64 rows
            const float* src = csrc + (size_t)(n0 + row) * R_DIM + ck;
            regs[2 * c]     = *(const f4*)src;
            regs[2 * c + 1] = *(const f4*)(src + 4);
        }
    };
    // convert + write into swizzled LDS image (after MFMA block)
    auto writeB = [&](int buf, const f4* regs) {
        #pragma unroll
        for (int c = 0; c < 2; ++c) {
            const int row = w * 16 + c * 8 + srow;
            f4 lo = regs[2 * c], hi = regs[2 * c + 1];
            half8 h = { (half_t)lo.x, (half_t)lo.y, (half_t)lo.z, (half_t)lo.w,
                        (half_t)hi.x, (half_t)hi.y, (half_t)hi.z, (half_t)hi.w };
            *(half8*)&sB[buf][row * BK + p8 * 8] = h;
        }
    };

    {
        f4 b0[4];
        loadB(kz, b0);
        stageA(0, kz);
        writeB(0, b0);
    }
    __syncthreads();

    const int l15 = lane & 15, l4 = lane >> 4;
    int buf = 0;
    for (int ks = 0; ks < NSTEP; ++ks) {
        f4 bn[4];
        const bool nxt = (ks + 1 < NSTEP);
        if (nxt) {
            loadB(kz + (ks + 1) * BK, bn);
            stageA(buf ^ 1, kz + (ks + 1) * BK);
        }
        #pragma unroll
        for (int ksub = 0; ksub < 2; ++ksub) {
            half8 af[4], bfr[2];
            const int cb = ksub * 4 + l4;          // logical col-block 0..7
            #pragma unroll
            for (int mi = 0; mi < 4; ++mi) {
                const int row = wr * 64 + mi * 16 + l15;
                af[mi] = *(const half8*)&sA[buf][row * BK + ((cb ^ (row & 7)) << 3)];
            }
            #pragma unroll
            for (int ni = 0; ni < 2; ++ni) {
                const int row = wc * 32 + ni * 16 + l15;
                bfr[ni] = *(const half8*)&sB[buf][row * BK + ((cb ^ (row & 7)) << 3)];
            }
            #pragma unroll
            for (int mi = 0; mi < 4; ++mi)
                #pragma unroll
                for (int ni = 0; ni < 2; ++ni)
                    acc[mi][ni] = __builtin_amdgcn_mfma_f32_16x16x32_f16(
                        af[mi], bfr[ni], acc[mi][ni], 0, 0, 0);
        }
        if (nxt) writeB(buf ^ 1, bn);
        __syncthreads();
        buf ^= 1;
    }

    float* P = part + (size_t)z * ((size_t)M_DIM * N_DIM);
    #pragma unroll
    for (int mi = 0; mi < 4; ++mi) {
        const int rb = m0 + wr * 64 + mi * 16 + l4 * 4;
        #pragma unroll
        for (int ni = 0; ni < 2; ++ni) {
            const int cc = n0 + wc * 32 + ni * 16 + l15;
            #pragma unroll
            for (int r = 0; r < 4; ++r)
                P[(size_t)(rb + r) * N_DIM + cc] = acc[mi][ni][r];
        }
    }
}

// ---------------- kernel 3: reduce split-K partials + root outer ----------
__global__ __launch_bounds__(256) void k_final(
    const float* __restrict__ part, const float* __restrict__ filler,
    const float* __restrict__ role, float* __restrict__ out)
{
    const int idx = (blockIdx.x * 256 + threadIdx.x) * 4;  // over 1M outputs
    const int mfi = idx >> 11;          // b*64+f
    const int s   = idx & 2047;
    f4 a = *(const f4*)(part + idx);
    #pragma unroll
    for (int z = 1; z < SPLITK; ++z) {
        f4 p = *(const f4*)(part + (size_t)z * (M_DIM * (size_t)N_DIM) + idx);
        a.x += p.x; a.y += p.y; a.z += p.z; a.w += p.w;
    }
    const float fl = filler[mfi];
    f4 ro = *(const f4*)(role + s);
    a.x += fl * ro.x; a.y += fl * ro.y; a.z += fl * ro.z; a.w += fl * ro.w;
    *(f4*)(out + idx) = a;
}

extern "C" void kernel_launch(void* const* d_in, const int* in_sizes, int n_in,
                              void* d_out, int out_size, void* d_ws, size_t ws_size,
                              hipStream_t stream)
{
    const float* x      = (const float*)d_in[0];
    const float* w1     = (const float*)d_in[1];
    const float* w2     = (const float*)d_in[2];
    const float* filler = (const float*)d_in[3];
    const float* cl     = (const float*)d_in[4];
    const float* cr     = (const float*)d_in[5];
    const float* role   = (const float*)d_in[6];
    float* out = (float*)d_out;

    char* ws = (char*)d_ws;
    half_t* Ah  = (half_t*)ws;                       // 512*4096*2   = 4 MiB
    float*  prt = (float*)(ws + (4u << 20));         // 4*512*2048*4 = 16 MiB

    hipLaunchKernelGGL(k_front, dim3(513), dim3(512), 0, stream,
                       x, w1, w2, Ah, out);
    hipLaunchKernelGGL(k_gemm,  dim3(N_DIM / BN, M_DIM / BM, SPLITK), dim3(256), 0, stream,
                       Ah, cl, cr, prt);
    hipLaunchKernelGGL(k_final, dim3(1024), dim3(256), 0, stream, prt, filler, role, out);
}

// Round 14
// 73.602 us; speedup vs baseline: 1.0328x; 1.0328x over previous
//
#include <hip/hip_runtime.h>
#include <stdint.h>

#define L_DIM 64
#define R_DIM 2048
#define M_DIM 512      // B*F
#define K_DIM 4096     // 2*R (concat arg1|arg2 along K)
#define N_DIM 2048

typedef _Float16 half_t;
typedef _Float16 half4 __attribute__((ext_vector_type(4)));
typedef _Float16 half8 __attribute__((ext_vector_type(8)));
typedef float f4 __attribute__((ext_vector_type(4)));
typedef float floatx4 __attribute__((ext_vector_type(4)));

// ---------------- kernel 1: front (513 blocks x 512 thr) ----------------
// blocks 0..511 : weighted reduce over L -> Ah [512][4096] fp16
// block  512    : w1/w2 row maxes
__global__ __launch_bounds__(512) void k_front(
    const float* __restrict__ x, const float* __restrict__ w1,
    const float* __restrict__ w2, half_t* __restrict__ Ah,
    float* __restrict__ out)
{
    const int tid = threadIdx.x;
    const int bid = blockIdx.x;

    if (bid < 512) {
        __shared__ float w1s[L_DIM], w2s[L_DIM];
        const int bf = bid;
        const int b  = bf >> 6;
        const int f  = bf & 63;
        if (tid < L_DIM) {
            w1s[tid] = w1[b * L_DIM + tid];
            w2s[tid] = w2[b * L_DIM + tid];
        }
        __syncthreads();
        const int r0 = tid * 4;                     // 512*4 = 2048 = R
        const f4* xp = (const f4*)(x + ((size_t)(b * 4096 + f)) * 2048 + r0);
        float a1x=0.f,a1y=0.f,a1z=0.f,a1w=0.f;
        float a2x=0.f,a2y=0.f,a2z=0.f,a2w=0.f;
        #pragma unroll 8
        for (int l = 0; l < L_DIM; ++l) {
            f4 v = __builtin_nontemporal_load(xp + (size_t)l * (64 * R_DIM / 4));
            float u1 = w1s[l], u2 = w2s[l];
            a1x += v.x*u1; a1y += v.y*u1; a1z += v.z*u1; a1w += v.w*u1;
            a2x += v.x*u2; a2y += v.y*u2; a2z += v.z*u2; a2w += v.w*u2;
        }
        half4 h1 = { (half_t)a1x, (half_t)a1y, (half_t)a1z, (half_t)a1w };
        half4 h2 = { (half_t)a2x, (half_t)a2y, (half_t)a2z, (half_t)a2w };
        *(half4*)(Ah + (size_t)bf * K_DIM + r0) = h1;
        *(half4*)(Ah + (size_t)bf * K_DIM + R_DIM + r0) = h2;
    } else {
        if (tid < 16) {
            const float* src = (tid < 8) ? w1 : w2;
            const int b8 = tid & 7;
            float m = -1.f;
            #pragma unroll 8
            for (int l = 0; l < L_DIM; ++l)
                m = fmaxf(m, src[b8 * L_DIM + l]);
            out[(size_t)M_DIM * N_DIM + tid] = m;
        }
    }
}

// ---------------- kernel 2: MFMA GEMM, 256x128 tiles, splitK=8 --------------
// A staged via global_load_lds (fp16 from ws). B staged from cons fp32
// directly: load-early -> convert -> swizzled ds_write after MFMA (T14).
// BM=256 halves cons re-reads vs R12 (M/BM = 2).
__device__ __forceinline__ void gload16(void* lds, const void* g)
{
    __builtin_amdgcn_global_load_lds(
        (const __attribute__((address_space(1))) void*)g,
        (__attribute__((address_space(3))) void*)lds, 16, 0, 0);
}

#define BM 256
#define BN 128
#define BK 64
#define SPLITK 8
#define KSEG (K_DIM / SPLITK)  // 512
#define NSTEP (KSEG / BK)      // 8
#define SA_HALF (BM * BK)      // 16384 halfs per buffer
#define SB_HALF (BN * BK)      // 8192 halfs per buffer

__global__ __launch_bounds__(512) void k_gemm(
    const half_t* __restrict__ Ah, const float* __restrict__ cl,
    const float* __restrict__ cr, float* __restrict__ part)
{
    extern __shared__ half_t smem[];    // 2*SA_HALF + 2*SB_HALF halfs = 96 KB
    half_t* sA0 = smem;
    half_t* sB0 = smem + 2 * SA_HALF;

    const int tid  = threadIdx.x;
    const int lane = tid & 63;
    const int w    = tid >> 6;           // wave 0..7
    const int wr   = w >> 1, wc = w & 1; // 4x2 wave grid, 64x64 each
    const int m0   = blockIdx.y * BM;
    const int n0   = blockIdx.x * BN;
    const int z    = blockIdx.z;
    const int kz   = z * KSEG;

    const int srow = lane >> 3;                    // row within 8-row chunk
    const int p8   = lane & 7;                     // physical 8-half slot
    const int scol = (p8 ^ srow) << 3;             // swizzled source col (halfs)
    // B source: z<4 -> cons_l (k in [0,2048)), z>=4 -> cons_r
    const float* csrc = (z < 4) ? cl : cr;

    const floatx4 fzero = { 0.f, 0.f, 0.f, 0.f };
    floatx4 acc[4][4];
    #pragma unroll
    for (int i = 0; i < 4; ++i)
        #pragma unroll
        for (int j = 0; j < 4; ++j) acc[i][j] = fzero;

    auto stageA = [&](int buf, int kt) {
        half_t* sA = sA0 + buf * SA_HALF;
        #pragma unroll
        for (int c = 0; c < 4; ++c) {
            const int rbase = w * 32 + c * 8;      // wave-uniform, 256 rows
            const int row   = rbase + srow;
            gload16(&sA[rbase * BK], Ah + (size_t)(m0 + row) * K_DIM + kt + scol);
        }
    };
    // load B fp32 into regs (issue early; swizzle folded into source col)
    auto loadB = [&](int kt, f4* regs) {
        const int ck = (kt & 2047) + scol;
        #pragma unroll
        for (int c = 0; c < 2; ++c) {
            const int row = w * 16 + c * 8 + srow; // 128 rows over 8 waves
            const float* src = csrc + (size_t)(n0 + row) * R_DIM + ck;
            regs[2 * c]     = *(const f4*)src;
            regs[2 * c + 1] = *(const f4*)(src + 4);
        }
    };
    // convert + write into swizzled LDS image (after MFMA block)
    auto writeB = [&](int buf, const f4* regs) {
        half_t* sB = sB0 + buf * SB_HALF;
        #pragma unroll
        for (int c = 0; c < 2; ++c) {
            const int row = w * 16 + c * 8 + srow;
            f4 lo = regs[2 * c], hi = regs[2 * c + 1];
            half8 h = { (half_t)lo.x, (half_t)lo.y, (half_t)lo.z, (half_t)lo.w,
                        (half_t)hi.x, (half_t)hi.y, (half_t)hi.z, (half_t)hi.w };
            *(half8*)&sB[row * BK + p8 * 8] = h;
        }
    };

    {
        f4 b0[4];
        loadB(kz, b0);
        stageA(0, kz);
        writeB(0, b0);
    }
    __syncthreads();

    const int l15 = lane & 15, l4 = lane >> 4;
    int buf = 0;
    for (int ks = 0; ks < NSTEP; ++ks) {
        f4 bn[4];
        const bool nxt = (ks + 1 < NSTEP);
        if (nxt) {
            loadB(kz + (ks + 1) * BK, bn);
            stageA(buf ^ 1, kz + (ks + 1) * BK);
        }
        half_t* sA = sA0 + buf * SA_HALF;
        half_t* sB = sB0 + buf * SB_HALF;
        #pragma unroll
        for (int ksub = 0; ksub < 2; ++ksub) {
            half8 af[4], bfr[4];
            const int cb = ksub * 4 + l4;          // logical col-block 0..7
            #pragma unroll
            for (int mi = 0; mi < 4; ++mi) {
                const int row = wr * 64 + mi * 16 + l15;
                af[mi] = *(const half8*)&sA[row * BK + ((cb ^ (row & 7)) << 3)];
            }
            #pragma unroll
            for (int ni = 0; ni < 4; ++ni) {
                const int row = wc * 64 + ni * 16 + l15;
                bfr[ni] = *(const half8*)&sB[row * BK + ((cb ^ (row & 7)) << 3)];
            }
            #pragma unroll
            for (int mi = 0; mi < 4; ++mi)
                #pragma unroll
                for (int ni = 0; ni < 4; ++ni)
                    acc[mi][ni] = __builtin_amdgcn_mfma_f32_16x16x32_f16(
                        af[mi], bfr[ni], acc[mi][ni], 0, 0, 0);
        }
        if (nxt) writeB(buf ^ 1, bn);
        __syncthreads();
        buf ^= 1;
    }

    float* P = part + (size_t)z * ((size_t)M_DIM * N_DIM);
    #pragma unroll
    for (int mi = 0; mi < 4; ++mi) {
        const int rb = m0 + wr * 64 + mi * 16 + l4 * 4;
        #pragma unroll
        for (int ni = 0; ni < 4; ++ni) {
            const int cc = n0 + wc * 64 + ni * 16 + l15;
            #pragma unroll
            for (int r = 0; r < 4; ++r)
                P[(size_t)(rb + r) * N_DIM + cc] = acc[mi][ni][r];
        }
    }
}

// ---------------- kernel 3: reduce split-K partials + root outer ----------
__global__ __launch_bounds__(256) void k_final(
    const float* __restrict__ part, const float* __restrict__ filler,
    const float* __restrict__ role, float* __restrict__ out)
{
    const int idx = (blockIdx.x * 256 + threadIdx.x) * 4;  // over 1M outputs
    const int mfi = idx >> 11;          // b*64+f
    const int s   = idx & 2047;
    f4 a = *(const f4*)(part + idx);
    #pragma unroll
    for (int z = 1; z < SPLITK; ++z) {
        f4 p = *(const f4*)(part + (size_t)z * (M_DIM * (size_t)N_DIM) + idx);
        a.x += p.x; a.y += p.y; a.z += p.z; a.w += p.w;
    }
    const float fl = filler[mfi];
    f4 ro = *(const f4*)(role + s);
    a.x += fl * ro.x; a.y += fl * ro.y; a.z += fl * ro.z; a.w += fl * ro.w;
    *(f4*)(out + idx) = a;
}

extern "C" void kernel_launch(void* const* d_in, const int* in_sizes, int n_in,
                              void* d_out, int out_size, void* d_ws, size_t ws_size,
                              hipStream_t stream)
{
    const float* x      = (const float*)d_in[0];
    const float* w1     = (const float*)d_in[1];
    const float* w2     = (const float*)d_in[2];
    const float* filler = (const float*)d_in[3];
    const float* cl     = (const float*)d_in[4];
    const float* cr     = (const float*)d_in[5];
    const float* role   = (const float*)d_in[6];
    float* out = (float*)d_out;

    char* ws = (char*)d_ws;
    half_t* Ah  = (half_t*)ws;                       // 512*4096*2   = 4 MiB
    float*  prt = (float*)(ws + (4u << 20));         // 8*512*2048*4 = 32 MiB

    const size_t lds_bytes = (2 * SA_HALF + 2 * SB_HALF) * sizeof(half_t); // 96 KB

    hipLaunchKernelGGL(k_front, dim3(513), dim3(512), 0, stream,
                       x, w1, w2, Ah, out);
    hipLaunchKernelGGL(k_gemm,  dim3(N_DIM / BN, M_DIM / BM, SPLITK), dim3(512),
                       lds_bytes, stream, Ah, cl, cr, prt);
    hipLaunchKernelGGL(k_final, dim3(1024), dim3(256), 0, stream, prt, filler, role, out);
}